// Round 13
// baseline (484.245 us; speedup 1.0000x reference)
//
#include <hip/hip_runtime.h>
#include <hip/hip_fp16.h>

#define N_NODES 50000
#define N_EDGES 800000
#define IN_DIM 16
#define HID 16
#define EDGE_DIM 8
#define GRAPH_DIM 8
#define N_LAYERS 3
#define HIST_BLOCKS ((N_EDGES + 255) / 256)        // 3125
#define PREP_BLOCKS ((N_NODES * HID + 255) / 256)  // 3125
#define SCAN_T 1024
#define SCAN_CH ((N_NODES + SCAN_T - 1) / SCAN_T)  // 49

typedef unsigned uint4v __attribute__((ext_vector_type(4)));

// 24-byte CSR record: fp16x8 edge attrs + src node id (+pad). One scattered
// store region per edge in fill (was two: csr_src[] + ea_h[]).
struct Rec { unsigned e0, e1, e2, e3; int src; int pad; };

__device__ __forceinline__ unsigned pack_h2(float lo, float hi) {
    __half2 h = __floats2half2_rn(lo, hi);
    return *reinterpret_cast<unsigned*>(&h);
}
__device__ __forceinline__ float2 unpack_h2(unsigned u) {
    __half2 h = *reinterpret_cast<__half2*>(&u);
    return __half22float2(h);
}

// ---------------------------------------------------------------------------
// prep body (shared by fused l=0 kernel and standalone l=1,2 kernel)
// ---------------------------------------------------------------------------
__device__ __forceinline__ void prep_one(int t, const float* __restrict__ x_in,
                                         const float* __restrict__ nnW,
                                         const float* __restrict__ nnb,
                                         const float* __restrict__ rootW,
                                         const float* __restrict__ bias,
                                         unsigned* __restrict__ zw_h,
                                         float* __restrict__ rb, int apply_relu) {
    int n = t >> 4;
    int o = t & 15;

    float xv[IN_DIM];
    const float* xr = x_in + n * IN_DIM;
#pragma unroll
    for (int i = 0; i < IN_DIM; ++i) {
        float v = xr[i];
        xv[i] = apply_relu ? fmaxf(v, 0.0f) : v;
    }

    float zk[EDGE_DIM];
#pragma unroll
    for (int k = 0; k < EDGE_DIM; ++k) zk[k] = 0.0f;
    float wv = 0.0f;
    float rv = bias[o];

#pragma unroll
    for (int i = 0; i < IN_DIM; ++i) {
        float xi = xv[i];
#pragma unroll
        for (int k = 0; k < EDGE_DIM; ++k) {
            zk[k] = fmaf(xi, nnW[k * 256 + i * 16 + o], zk[k]);
        }
        wv = fmaf(xi, nnb[i * 16 + o], wv);
        rv = fmaf(xi, rootW[i * 16 + o], rv);
    }

    unsigned* zn = zw_h + (size_t)n * 80;
#pragma unroll
    for (int kp = 0; kp < 4; ++kp) zn[kp * 16 + o] = pack_h2(zk[2 * kp], zk[2 * kp + 1]);
    zn[64 + o] = pack_h2(wv, 0.0f);
    rb[n * 16 + o] = rv;
}

// ---------------------------------------------------------------------------
// fused: hist (blocks 0..3124) + prep layer 0 (blocks 3125..6249).
// Independent work; hist's latency hides under prep0's compute.
// deg must be pre-zeroed (hipMemsetAsync).
// ---------------------------------------------------------------------------
__global__ __launch_bounds__(256)
void hist_prep0_kernel(const int* __restrict__ ei, int* __restrict__ deg,
                       const float* __restrict__ x, const float* __restrict__ nnW,
                       const float* __restrict__ nnb, const float* __restrict__ rootW,
                       const float* __restrict__ bias,
                       unsigned* __restrict__ zw_h, float* __restrict__ rb) {
    if (blockIdx.x < HIST_BLOCKS) {
        int e = blockIdx.x * 256 + threadIdx.x;
        if (e < N_EDGES) atomicAdd(&deg[ei[N_EDGES + e]], 1);
    } else {
        int t = (blockIdx.x - HIST_BLOCKS) * 256 + threadIdx.x;
        if (t < N_NODES * HID)
            prep_one(t, x, nnW, nnb, rootW, bias, zw_h, rb, 0);
    }
}

// ---------------------------------------------------------------------------
// single-block exclusive scan of deg[0..N) -> offs; rewrites deg as cursor.
// Two-pass per thread chunk (49 elems) + Hillis-Steele over 1024 partials.
// Replaces the previous 3-kernel scan chain (saves 2 dispatch gaps).
// ---------------------------------------------------------------------------
__global__ __launch_bounds__(SCAN_T)
void scan_kernel(int* __restrict__ deg, int* __restrict__ offs) {
    __shared__ int s[SCAN_T];
    int tid = threadIdx.x;
    int base = tid * SCAN_CH;

    int sum = 0;
    for (int i = 0; i < SCAN_CH; ++i) {
        int idx = base + i;
        if (idx < N_NODES) sum += deg[idx];
    }
    s[tid] = sum;
    __syncthreads();
    for (int off = 1; off < SCAN_T; off <<= 1) {
        int t = (tid >= off) ? s[tid - off] : 0;
        __syncthreads();
        s[tid] += t;
        __syncthreads();
    }
    int run = s[tid] - sum;   // exclusive prefix of this chunk
    for (int i = 0; i < SCAN_CH; ++i) {
        int idx = base + i;
        if (idx < N_NODES) {
            int d = deg[idx];
            offs[idx] = run;
            deg[idx] = run;   // deg becomes the fill cursor
            run += d;
        }
    }
    if (tid == 0) offs[N_NODES] = N_EDGES;
}

// ---------------------------------------------------------------------------
// fill: scatter edges into CSR order as single 24B records.
// ---------------------------------------------------------------------------
__global__ __launch_bounds__(256)
void fill_kernel(const int* __restrict__ ei, const float* __restrict__ ea,
                 int* __restrict__ cur, Rec* __restrict__ csr) {
    int e = blockIdx.x * blockDim.x + threadIdx.x;
    if (e >= N_EDGES) return;
    int src = ei[e];
    int dst = ei[N_EDGES + e];
    const float4* eap = (const float4*)(ea + (size_t)e * EDGE_DIM);
    float4 e0 = eap[0];
    float4 e1 = eap[1];
    Rec r;
    r.e0 = pack_h2(e0.x, e0.y);
    r.e1 = pack_h2(e0.z, e0.w);
    r.e2 = pack_h2(e1.x, e1.y);
    r.e3 = pack_h2(e1.z, e1.w);
    r.src = src;
    r.pad = 0;
    int j = atomicAdd(&cur[dst], 1);
    csr[j] = r;
}

// ---------------------------------------------------------------------------
// standalone prep for layers 1,2 (relu on input)
// ---------------------------------------------------------------------------
__global__ __launch_bounds__(256)
void prep_kernel(const float* __restrict__ x_in, const float* __restrict__ nnW,
                 const float* __restrict__ nnb, const float* __restrict__ rootW,
                 const float* __restrict__ bias,
                 unsigned* __restrict__ zw_h, float* __restrict__ rb) {
    int t = blockIdx.x * blockDim.x + threadIdx.x;
    if (t < N_NODES * HID)
        prep_one(t, x_in, nnW, nnb, rootW, bias, zw_h, rb, 1);
}

// ---------------------------------------------------------------------------
// per-edge accumulate helper (9 fmafs into acc)
// ---------------------------------------------------------------------------
__device__ __forceinline__ void edge_accum(const unsigned* __restrict__ zp,
                                           uint4v rec, int o, float& acc) {
    unsigned q0 = zp[o];
    unsigned q1 = zp[16 + o];
    unsigned q2 = zp[32 + o];
    unsigned q3 = zp[48 + o];
    unsigned q4 = zp[64 + o];
    float2 e01 = unpack_h2(rec.x);
    float2 e23 = unpack_h2(rec.y);
    float2 e45 = unpack_h2(rec.z);
    float2 e67 = unpack_h2(rec.w);
    float2 z01 = unpack_h2(q0);
    float2 z23 = unpack_h2(q1);
    float2 z45 = unpack_h2(q2);
    float2 z67 = unpack_h2(q3);
    float2 w_  = unpack_h2(q4);
    acc += w_.x;
    acc = fmaf(e01.x, z01.x, acc);
    acc = fmaf(e01.y, z01.y, acc);
    acc = fmaf(e23.x, z23.x, acc);
    acc = fmaf(e23.y, z23.y, acc);
    acc = fmaf(e45.x, z45.x, acc);
    acc = fmaf(e45.y, z45.y, acc);
    acc = fmaf(e67.x, z67.x, acc);
    acc = fmaf(e67.y, z67.y, acc);
}

// ---------------------------------------------------------------------------
// agg: 16 lanes per node; x2 unrolled dual accumulators (MLP).
// DO_HEAD fuses the output head on the last layer.
// ---------------------------------------------------------------------------
template <bool DO_HEAD>
__global__ __launch_bounds__(256)
void agg_kernel(const int* __restrict__ offs,       // [N+1]
                const Rec* __restrict__ csr,        // [E] 24B records
                const unsigned* __restrict__ zw_h,  // [N,5,16] half2
                float* __restrict__ buf,            // in: rb, out: pre-ReLU
                const float* __restrict__ gf,       // [8,N]   (head only)
                const float* __restrict__ hW,       // [24]    (head only)
                const float* __restrict__ hb,       // [1]     (head only)
                float* __restrict__ out) {          // [N]     (head only)
    int tid = threadIdx.x;
    int o = tid & 15;
    int n = blockIdx.x * 16 + (tid >> 4);
    if (n >= N_NODES) return;

    float acc0 = buf[n * HID + o];
    float acc1 = 0.0f;
    int jb = offs[n], je = offs[n + 1];
    int j = jb;
    for (; j + 1 < je; j += 2) {
        Rec r0 = csr[j];
        Rec r1 = csr[j + 1];
        uint4v a0 = {r0.e0, r0.e1, r0.e2, r0.e3};
        uint4v a1 = {r1.e0, r1.e1, r1.e2, r1.e3};
        edge_accum(zw_h + (size_t)r0.src * 80, a0, o, acc0);
        edge_accum(zw_h + (size_t)r1.src * 80, a1, o, acc1);
    }
    if (j < je) {
        Rec r0 = csr[j];
        uint4v a0 = {r0.e0, r0.e1, r0.e2, r0.e3};
        edge_accum(zw_h + (size_t)r0.src * 80, a0, o, acc0);
    }
    float acc = acc0 + acc1;

    if (!DO_HEAD) {
        buf[n * HID + o] = acc;
    } else {
        float h = fmaxf(acc, 0.0f) * hW[o];
        if (o < GRAPH_DIM) h = fmaf(gf[o * N_NODES + n], hW[HID + o], h);
#pragma unroll
        for (int off = 8; off > 0; off >>= 1) h += __shfl_xor(h, off, 16);
        if (o == 0) out[n] = h + hb[0];
    }
}

extern "C" void kernel_launch(void* const* d_in, const int* in_sizes, int n_in,
                              void* d_out, int out_size, void* d_ws, size_t ws_size,
                              hipStream_t stream) {
    const float* x     = (const float*)d_in[0];
    const int*   ei    = (const int*)d_in[1];
    const float* ea    = (const float*)d_in[2];
    const float* gf    = (const float*)d_in[3];
    const float* nnW   = (const float*)d_in[4];
    const float* nnb   = (const float*)d_in[5];
    const float* rootW = (const float*)d_in[6];
    const float* bias  = (const float*)d_in[7];
    const float* hW    = (const float*)d_in[8];
    const float* hb    = (const float*)d_in[9];
    float* out = (float*)d_out;

    // workspace (~42.0 MB, within the proven 42.2 MB envelope):
    //   zw_h: N*80 u32 = 16.0 MB
    //   csr:  E Rec(24B) = 19.2 MB
    //   bufA/bufB: 3.2 MB each
    //   deg (doubles as cursor), offs(N+1)
    unsigned* zw_h = (unsigned*)d_ws;
    Rec* csr   = (Rec*)(zw_h + (size_t)N_NODES * 80);        // @16.0 MB (8B-aligned)
    float* bufA = (float*)((char*)csr + (size_t)N_EDGES * sizeof(Rec));
    float* bufB = bufA + (size_t)N_NODES * HID;
    int* deg    = (int*)(bufB + (size_t)N_NODES * HID);
    int* offs   = deg + N_NODES;

    dim3 blk(256);
    dim3 grid_e(HIST_BLOCKS);                    // 3125
    dim3 grid_hp(HIST_BLOCKS + PREP_BLOCKS);     // 6250
    dim3 grid_no(PREP_BLOCKS);                   // 3125
    dim3 grid_a((N_NODES + 15) / 16);            // 3125

    // 9 dispatches total
    hipMemsetAsync(deg, 0, N_NODES * sizeof(int), stream);
    hist_prep0_kernel<<<grid_hp, blk, 0, stream>>>(ei, deg, x, nnW, nnb, rootW, bias,
                                                   zw_h, bufA);
    scan_kernel<<<1, SCAN_T, 0, stream>>>(deg, offs);
    fill_kernel<<<grid_e, blk, 0, stream>>>(ei, ea, deg, csr);

    agg_kernel<false><<<grid_a, blk, 0, stream>>>(offs, csr, zw_h, bufA,
                                                  nullptr, nullptr, nullptr, nullptr);
    // layer 1
    prep_kernel<<<grid_no, blk, 0, stream>>>(bufA, nnW + 2048, nnb + 256,
                                             rootW + 256, bias + 16, zw_h, bufB);
    agg_kernel<false><<<grid_a, blk, 0, stream>>>(offs, csr, zw_h, bufB,
                                                  nullptr, nullptr, nullptr, nullptr);
    // layer 2 (head fused)
    prep_kernel<<<grid_no, blk, 0, stream>>>(bufB, nnW + 4096, nnb + 512,
                                             rootW + 512, bias + 32, zw_h, bufA);
    agg_kernel<true><<<grid_a, blk, 0, stream>>>(offs, csr, zw_h, bufA,
                                                 gf, hW, hb, out);
}

// Round 14
// 370.238 us; speedup vs baseline: 1.3079x; 1.3079x over previous
//
#include <hip/hip_runtime.h>
#include <hip/hip_fp16.h>

#define N_NODES 50000
#define N_EDGES 800000
#define IN_DIM 16
#define HID 16
#define EDGE_DIM 8
#define GRAPH_DIM 8
#define N_LAYERS 3
#define HIST_BLOCKS ((N_EDGES + 255) / 256)        // 3125
#define PREP_BLOCKS ((N_NODES * HID + 255) / 256)  // 3125
#define SCAN_BS 256
#define SCAN_NB ((N_NODES + SCAN_BS - 1) / SCAN_BS)   // 196

typedef unsigned uint4v __attribute__((ext_vector_type(4)));

// 24-byte CSR record: fp16x8 edge attrs + src node id (+pad).
struct Rec { unsigned e0, e1, e2, e3; int src; int pad; };

__device__ __forceinline__ unsigned pack_h2(float lo, float hi) {
    __half2 h = __floats2half2_rn(lo, hi);
    return *reinterpret_cast<unsigned*>(&h);
}
__device__ __forceinline__ float2 unpack_h2(unsigned u) {
    __half2 h = *reinterpret_cast<__half2*>(&u);
    return __half22float2(h);
}

// ---------------------------------------------------------------------------
// prep body (shared)
// ---------------------------------------------------------------------------
__device__ __forceinline__ void prep_one(int t, const float* __restrict__ x_in,
                                         const float* __restrict__ nnW,
                                         const float* __restrict__ nnb,
                                         const float* __restrict__ rootW,
                                         const float* __restrict__ bias,
                                         unsigned* __restrict__ zw_h,
                                         float* __restrict__ rb, int apply_relu) {
    int n = t >> 4;
    int o = t & 15;

    float xv[IN_DIM];
    const float* xr = x_in + n * IN_DIM;
#pragma unroll
    for (int i = 0; i < IN_DIM; ++i) {
        float v = xr[i];
        xv[i] = apply_relu ? fmaxf(v, 0.0f) : v;
    }

    float zk[EDGE_DIM];
#pragma unroll
    for (int k = 0; k < EDGE_DIM; ++k) zk[k] = 0.0f;
    float wv = 0.0f;
    float rv = bias[o];

#pragma unroll
    for (int i = 0; i < IN_DIM; ++i) {
        float xi = xv[i];
#pragma unroll
        for (int k = 0; k < EDGE_DIM; ++k) {
            zk[k] = fmaf(xi, nnW[k * 256 + i * 16 + o], zk[k]);
        }
        wv = fmaf(xi, nnb[i * 16 + o], wv);
        rv = fmaf(xi, rootW[i * 16 + o], rv);
    }

    unsigned* zn = zw_h + (size_t)n * 80;
#pragma unroll
    for (int kp = 0; kp < 4; ++kp) zn[kp * 16 + o] = pack_h2(zk[2 * kp], zk[2 * kp + 1]);
    zn[64 + o] = pack_h2(wv, 0.0f);
    rb[n * 16 + o] = rv;
}

// ---------------------------------------------------------------------------
// fused: hist (blocks 0..3124) + prep layer 0 (blocks 3125..6249).
// deg must be pre-zeroed (hipMemsetAsync).
// ---------------------------------------------------------------------------
__global__ __launch_bounds__(256)
void hist_prep0_kernel(const int* __restrict__ ei, int* __restrict__ deg,
                       const float* __restrict__ x, const float* __restrict__ nnW,
                       const float* __restrict__ nnb, const float* __restrict__ rootW,
                       const float* __restrict__ bias,
                       unsigned* __restrict__ zw_h, float* __restrict__ rb) {
    if (blockIdx.x < HIST_BLOCKS) {
        int e = blockIdx.x * 256 + threadIdx.x;
        if (e < N_EDGES) atomicAdd(&deg[ei[N_EDGES + e]], 1);
    } else {
        int t = (blockIdx.x - HIST_BLOCKS) * 256 + threadIdx.x;
        if (t < N_NODES * HID)
            prep_one(t, x, nnW, nnb, rootW, bias, zw_h, rb, 0);
    }
}

// ---------------------------------------------------------------------------
// scan1: per-block exclusive scan of deg (196 blocks, coalesced, LDS H-S).
// Writes block-local offs + per-block totals bsum.  (R13 lesson: the scan
// must be grid-parallel — a 1-block 50K scan cost 124us.)
// ---------------------------------------------------------------------------
__global__ __launch_bounds__(SCAN_BS)
void scan1_kernel(const int* __restrict__ deg, int* __restrict__ offs,
                  int* __restrict__ bsum) {
    __shared__ int s[SCAN_BS];
    int tid = threadIdx.x;
    int i = blockIdx.x * SCAN_BS + tid;
    int v = (i < N_NODES) ? deg[i] : 0;
    s[tid] = v;
    __syncthreads();
    for (int off = 1; off < SCAN_BS; off <<= 1) {
        int t = (tid >= off) ? s[tid - off] : 0;
        __syncthreads();
        s[tid] += t;
        __syncthreads();
    }
    if (i < N_NODES) offs[i] = s[tid] - v;           // exclusive, block-local
    if (tid == SCAN_BS - 1) bsum[blockIdx.x] = s[tid];
}

// ---------------------------------------------------------------------------
// scan23: each block independently computes base = sum(bsum[0..blockIdx-1])
// (256-thread LDS reduction over the 196-entry bsum, L2-resident), applies it
// to offs, and writes the fill cursor into deg. Removes the serial
// middle-kernel dependency -> 2-dispatch scan chain.
// ---------------------------------------------------------------------------
__global__ __launch_bounds__(SCAN_BS)
void scan23_kernel(int* __restrict__ offs, const int* __restrict__ bsum,
                   int* __restrict__ deg) {
    __shared__ int s[SCAN_BS];
    int tid = threadIdx.x;
    s[tid] = (tid < (int)blockIdx.x) ? bsum[tid] : 0;   // blockIdx <= 195 < 256
    __syncthreads();
    for (int off = SCAN_BS / 2; off > 0; off >>= 1) {
        if (tid < off) s[tid] += s[tid + off];
        __syncthreads();
    }
    int base = s[0];
    int i = blockIdx.x * SCAN_BS + tid;
    if (i < N_NODES) {
        int o = offs[i] + base;
        offs[i] = o;
        deg[i] = o;           // deg becomes the fill cursor
    }
    if (i == 0) offs[N_NODES] = N_EDGES;
}

// ---------------------------------------------------------------------------
// fill: scatter edges into CSR order as single 24B records.
// ---------------------------------------------------------------------------
__global__ __launch_bounds__(256)
void fill_kernel(const int* __restrict__ ei, const float* __restrict__ ea,
                 int* __restrict__ cur, Rec* __restrict__ csr) {
    int e = blockIdx.x * blockDim.x + threadIdx.x;
    if (e >= N_EDGES) return;
    int src = ei[e];
    int dst = ei[N_EDGES + e];
    const float4* eap = (const float4*)(ea + (size_t)e * EDGE_DIM);
    float4 e0 = eap[0];
    float4 e1 = eap[1];
    Rec r;
    r.e0 = pack_h2(e0.x, e0.y);
    r.e1 = pack_h2(e0.z, e0.w);
    r.e2 = pack_h2(e1.x, e1.y);
    r.e3 = pack_h2(e1.z, e1.w);
    r.src = src;
    r.pad = 0;
    int j = atomicAdd(&cur[dst], 1);
    csr[j] = r;
}

// ---------------------------------------------------------------------------
// standalone prep for layers 1,2 (relu on input)
// ---------------------------------------------------------------------------
__global__ __launch_bounds__(256)
void prep_kernel(const float* __restrict__ x_in, const float* __restrict__ nnW,
                 const float* __restrict__ nnb, const float* __restrict__ rootW,
                 const float* __restrict__ bias,
                 unsigned* __restrict__ zw_h, float* __restrict__ rb) {
    int t = blockIdx.x * blockDim.x + threadIdx.x;
    if (t < N_NODES * HID)
        prep_one(t, x_in, nnW, nnb, rootW, bias, zw_h, rb, 1);
}

// ---------------------------------------------------------------------------
// per-edge accumulate helper (9 fmafs into acc)
// ---------------------------------------------------------------------------
__device__ __forceinline__ void edge_accum(const unsigned* __restrict__ zp,
                                           uint4v rec, int o, float& acc) {
    unsigned q0 = zp[o];
    unsigned q1 = zp[16 + o];
    unsigned q2 = zp[32 + o];
    unsigned q3 = zp[48 + o];
    unsigned q4 = zp[64 + o];
    float2 e01 = unpack_h2(rec.x);
    float2 e23 = unpack_h2(rec.y);
    float2 e45 = unpack_h2(rec.z);
    float2 e67 = unpack_h2(rec.w);
    float2 z01 = unpack_h2(q0);
    float2 z23 = unpack_h2(q1);
    float2 z45 = unpack_h2(q2);
    float2 z67 = unpack_h2(q3);
    float2 w_  = unpack_h2(q4);
    acc += w_.x;
    acc = fmaf(e01.x, z01.x, acc);
    acc = fmaf(e01.y, z01.y, acc);
    acc = fmaf(e23.x, z23.x, acc);
    acc = fmaf(e23.y, z23.y, acc);
    acc = fmaf(e45.x, z45.x, acc);
    acc = fmaf(e45.y, z45.y, acc);
    acc = fmaf(e67.x, z67.x, acc);
    acc = fmaf(e67.y, z67.y, acc);
}

// ---------------------------------------------------------------------------
// agg: 16 lanes per node; x2 unrolled dual accumulators.
// DO_HEAD fuses the output head on the last layer.
// ---------------------------------------------------------------------------
template <bool DO_HEAD>
__global__ __launch_bounds__(256)
void agg_kernel(const int* __restrict__ offs,       // [N+1]
                const Rec* __restrict__ csr,        // [E] 24B records
                const unsigned* __restrict__ zw_h,  // [N,5,16] half2
                float* __restrict__ buf,            // in: rb, out: pre-ReLU
                const float* __restrict__ gf,       // [8,N]   (head only)
                const float* __restrict__ hW,       // [24]    (head only)
                const float* __restrict__ hb,       // [1]     (head only)
                float* __restrict__ out) {          // [N]     (head only)
    int tid = threadIdx.x;
    int o = tid & 15;
    int n = blockIdx.x * 16 + (tid >> 4);
    if (n >= N_NODES) return;

    float acc0 = buf[n * HID + o];
    float acc1 = 0.0f;
    int jb = offs[n], je = offs[n + 1];
    int j = jb;
    for (; j + 1 < je; j += 2) {
        Rec r0 = csr[j];
        Rec r1 = csr[j + 1];
        uint4v a0 = {r0.e0, r0.e1, r0.e2, r0.e3};
        uint4v a1 = {r1.e0, r1.e1, r1.e2, r1.e3};
        edge_accum(zw_h + (size_t)r0.src * 80, a0, o, acc0);
        edge_accum(zw_h + (size_t)r1.src * 80, a1, o, acc1);
    }
    if (j < je) {
        Rec r0 = csr[j];
        uint4v a0 = {r0.e0, r0.e1, r0.e2, r0.e3};
        edge_accum(zw_h + (size_t)r0.src * 80, a0, o, acc0);
    }
    float acc = acc0 + acc1;

    if (!DO_HEAD) {
        buf[n * HID + o] = acc;
    } else {
        float h = fmaxf(acc, 0.0f) * hW[o];
        if (o < GRAPH_DIM) h = fmaf(gf[o * N_NODES + n], hW[HID + o], h);
#pragma unroll
        for (int off = 8; off > 0; off >>= 1) h += __shfl_xor(h, off, 16);
        if (o == 0) out[n] = h + hb[0];
    }
}

extern "C" void kernel_launch(void* const* d_in, const int* in_sizes, int n_in,
                              void* d_out, int out_size, void* d_ws, size_t ws_size,
                              hipStream_t stream) {
    const float* x     = (const float*)d_in[0];
    const int*   ei    = (const int*)d_in[1];
    const float* ea    = (const float*)d_in[2];
    const float* gf    = (const float*)d_in[3];
    const float* nnW   = (const float*)d_in[4];
    const float* nnb   = (const float*)d_in[5];
    const float* rootW = (const float*)d_in[6];
    const float* bias  = (const float*)d_in[7];
    const float* hW    = (const float*)d_in[8];
    const float* hb    = (const float*)d_in[9];
    float* out = (float*)d_out;

    // workspace (~42.0 MB):
    unsigned* zw_h = (unsigned*)d_ws;
    Rec* csr   = (Rec*)(zw_h + (size_t)N_NODES * 80);        // @16.0 MB
    float* bufA = (float*)((char*)csr + (size_t)N_EDGES * sizeof(Rec));
    float* bufB = bufA + (size_t)N_NODES * HID;
    int* deg    = (int*)(bufB + (size_t)N_NODES * HID);
    int* offs   = deg + N_NODES;
    int* bsum   = offs + N_NODES + 8;

    dim3 blk(256);
    dim3 grid_e(HIST_BLOCKS);                    // 3125
    dim3 grid_hp(HIST_BLOCKS + PREP_BLOCKS);     // 6250
    dim3 grid_no(PREP_BLOCKS);                   // 3125
    dim3 grid_a((N_NODES + 15) / 16);            // 3125

    // 10 dispatches total
    hipMemsetAsync(deg, 0, N_NODES * sizeof(int), stream);
    hist_prep0_kernel<<<grid_hp, blk, 0, stream>>>(ei, deg, x, nnW, nnb, rootW, bias,
                                                   zw_h, bufA);
    scan1_kernel<<<SCAN_NB, SCAN_BS, 0, stream>>>(deg, offs, bsum);
    scan23_kernel<<<SCAN_NB, SCAN_BS, 0, stream>>>(offs, bsum, deg);
    fill_kernel<<<grid_e, blk, 0, stream>>>(ei, ea, deg, csr);

    agg_kernel<false><<<grid_a, blk, 0, stream>>>(offs, csr, zw_h, bufA,
                                                  nullptr, nullptr, nullptr, nullptr);
    // layer 1
    prep_kernel<<<grid_no, blk, 0, stream>>>(bufA, nnW + 2048, nnb + 256,
                                             rootW + 256, bias + 16, zw_h, bufB);
    agg_kernel<false><<<grid_a, blk, 0, stream>>>(offs, csr, zw_h, bufB,
                                                  nullptr, nullptr, nullptr, nullptr);
    // layer 2 (head fused)
    prep_kernel<<<grid_no, blk, 0, stream>>>(bufB, nnW + 4096, nnb + 512,
                                             rootW + 512, bias + 32, zw_h, bufA);
    agg_kernel<true><<<grid_a, blk, 0, stream>>>(offs, csr, zw_h, bufA,
                                                 gf, hW, hb, out);
}

// Round 15
// 348.338 us; speedup vs baseline: 1.3902x; 1.0629x over previous
//
#include <hip/hip_runtime.h>
#include <hip/hip_fp16.h>

#define N_NODES 50000
#define N_EDGES 800000
#define IN_DIM 16
#define HID 16
#define EDGE_DIM 8
#define GRAPH_DIM 8
#define HIST_BLOCKS ((N_EDGES + 255) / 256)        // 3125
#define PREP_BLOCKS ((N_NODES * HID + 255) / 256)  // 3125
#define SCAN_BS 256
#define SCAN_NB ((N_NODES + SCAN_BS - 1) / SCAN_BS)   // 196

typedef unsigned uint4v __attribute__((ext_vector_type(4)));

// 24-byte CSR record: fp16x8 edge attrs + src node id (+pad).
struct Rec { unsigned e0, e1, e2, e3; int src; int pad; };

__device__ __forceinline__ unsigned pack_h2(float lo, float hi) {
    __half2 h = __floats2half2_rn(lo, hi);
    return *reinterpret_cast<unsigned*>(&h);
}
__device__ __forceinline__ float2 unpack_h2(unsigned u) {
    __half2 h = *reinterpret_cast<__half2*>(&u);
    return __half22float2(h);
}

// ---------------------------------------------------------------------------
// prep math from a register array xv[16] -> zw row + rb value for (n,o)
// ---------------------------------------------------------------------------
__device__ __forceinline__ void prep_core(const float* __restrict__ xv, int n, int o,
                                          const float* __restrict__ nnW,
                                          const float* __restrict__ nnb,
                                          const float* __restrict__ rootW,
                                          const float* __restrict__ bias,
                                          unsigned* __restrict__ zw_h,
                                          float* __restrict__ rb) {
    float zk[EDGE_DIM];
#pragma unroll
    for (int k = 0; k < EDGE_DIM; ++k) zk[k] = 0.0f;
    float wv = 0.0f;
    float rv = bias[o];
#pragma unroll
    for (int i = 0; i < IN_DIM; ++i) {
        float xi = xv[i];
#pragma unroll
        for (int k = 0; k < EDGE_DIM; ++k) {
            zk[k] = fmaf(xi, nnW[k * 256 + i * 16 + o], zk[k]);
        }
        wv = fmaf(xi, nnb[i * 16 + o], wv);
        rv = fmaf(xi, rootW[i * 16 + o], rv);
    }
    unsigned* zn = zw_h + (size_t)n * 80;
#pragma unroll
    for (int kp = 0; kp < 4; ++kp) zn[kp * 16 + o] = pack_h2(zk[2 * kp], zk[2 * kp + 1]);
    zn[64 + o] = pack_h2(wv, 0.0f);
    rb[n * 16 + o] = rv;
}

__device__ __forceinline__ void prep_one(int t, const float* __restrict__ x_in,
                                         const float* __restrict__ nnW,
                                         const float* __restrict__ nnb,
                                         const float* __restrict__ rootW,
                                         const float* __restrict__ bias,
                                         unsigned* __restrict__ zw_h,
                                         float* __restrict__ rb, int apply_relu) {
    int n = t >> 4;
    int o = t & 15;
    float xv[IN_DIM];
    const float* xr = x_in + n * IN_DIM;
#pragma unroll
    for (int i = 0; i < IN_DIM; ++i) {
        float v = xr[i];
        xv[i] = apply_relu ? fmaxf(v, 0.0f) : v;
    }
    prep_core(xv, n, o, nnW, nnb, rootW, bias, zw_h, rb);
}

// ---------------------------------------------------------------------------
// fused: hist (blocks 0..3124) + prep layer 0 (blocks 3125..6249).
// deg must be pre-zeroed (hipMemsetAsync).
// ---------------------------------------------------------------------------
__global__ __launch_bounds__(256)
void hist_prep0_kernel(const int* __restrict__ ei, int* __restrict__ deg,
                       const float* __restrict__ x, const float* __restrict__ nnW,
                       const float* __restrict__ nnb, const float* __restrict__ rootW,
                       const float* __restrict__ bias,
                       unsigned* __restrict__ zw_h, float* __restrict__ rb) {
    if (blockIdx.x < HIST_BLOCKS) {
        int e = blockIdx.x * 256 + threadIdx.x;
        if (e < N_EDGES) atomicAdd(&deg[ei[N_EDGES + e]], 1);
    } else {
        int t = (blockIdx.x - HIST_BLOCKS) * 256 + threadIdx.x;
        if (t < N_NODES * HID)
            prep_one(t, x, nnW, nnb, rootW, bias, zw_h, rb, 0);
    }
}

// ---------------------------------------------------------------------------
// scan1 + scan23: grid-parallel 2-dispatch scan (R13 lesson: never 1 block)
// ---------------------------------------------------------------------------
__global__ __launch_bounds__(SCAN_BS)
void scan1_kernel(const int* __restrict__ deg, int* __restrict__ offs,
                  int* __restrict__ bsum) {
    __shared__ int s[SCAN_BS];
    int tid = threadIdx.x;
    int i = blockIdx.x * SCAN_BS + tid;
    int v = (i < N_NODES) ? deg[i] : 0;
    s[tid] = v;
    __syncthreads();
    for (int off = 1; off < SCAN_BS; off <<= 1) {
        int t = (tid >= off) ? s[tid - off] : 0;
        __syncthreads();
        s[tid] += t;
        __syncthreads();
    }
    if (i < N_NODES) offs[i] = s[tid] - v;
    if (tid == SCAN_BS - 1) bsum[blockIdx.x] = s[tid];
}

__global__ __launch_bounds__(SCAN_BS)
void scan23_kernel(int* __restrict__ offs, const int* __restrict__ bsum,
                   int* __restrict__ deg) {
    __shared__ int s[SCAN_BS];
    int tid = threadIdx.x;
    s[tid] = (tid < (int)blockIdx.x) ? bsum[tid] : 0;
    __syncthreads();
    for (int off = SCAN_BS / 2; off > 0; off >>= 1) {
        if (tid < off) s[tid] += s[tid + off];
        __syncthreads();
    }
    int base = s[0];
    int i = blockIdx.x * SCAN_BS + tid;
    if (i < N_NODES) {
        int o = offs[i] + base;
        offs[i] = o;
        deg[i] = o;           // deg becomes the fill cursor
    }
    if (i == 0) offs[N_NODES] = N_EDGES;
}

// ---------------------------------------------------------------------------
// fill: scatter edges into CSR order as single 24B records.
// ---------------------------------------------------------------------------
__global__ __launch_bounds__(256)
void fill_kernel(const int* __restrict__ ei, const float* __restrict__ ea,
                 int* __restrict__ cur, Rec* __restrict__ csr) {
    int e = blockIdx.x * blockDim.x + threadIdx.x;
    if (e >= N_EDGES) return;
    int src = ei[e];
    int dst = ei[N_EDGES + e];
    const float4* eap = (const float4*)(ea + (size_t)e * EDGE_DIM);
    float4 e0 = eap[0];
    float4 e1 = eap[1];
    Rec r;
    r.e0 = pack_h2(e0.x, e0.y);
    r.e1 = pack_h2(e0.z, e0.w);
    r.e2 = pack_h2(e1.x, e1.y);
    r.e3 = pack_h2(e1.z, e1.w);
    r.src = src;
    r.pad = 0;
    int j = atomicAdd(&cur[dst], 1);
    csr[j] = r;
}

// ---------------------------------------------------------------------------
// standalone prep for layers 1,2 (fallback path only)
// ---------------------------------------------------------------------------
__global__ __launch_bounds__(256)
void prep_kernel(const float* __restrict__ x_in, const float* __restrict__ nnW,
                 const float* __restrict__ nnb, const float* __restrict__ rootW,
                 const float* __restrict__ bias,
                 unsigned* __restrict__ zw_h, float* __restrict__ rb) {
    int t = blockIdx.x * blockDim.x + threadIdx.x;
    if (t < N_NODES * HID)
        prep_one(t, x_in, nnW, nnb, rootW, bias, zw_h, rb, 1);
}

// ---------------------------------------------------------------------------
// per-edge accumulate helper (9 fmafs into acc)
// ---------------------------------------------------------------------------
__device__ __forceinline__ void edge_accum(const unsigned* __restrict__ zp,
                                           uint4v rec, int o, float& acc) {
    unsigned q0 = zp[o];
    unsigned q1 = zp[16 + o];
    unsigned q2 = zp[32 + o];
    unsigned q3 = zp[48 + o];
    unsigned q4 = zp[64 + o];
    float2 e01 = unpack_h2(rec.x);
    float2 e23 = unpack_h2(rec.y);
    float2 e45 = unpack_h2(rec.z);
    float2 e67 = unpack_h2(rec.w);
    float2 z01 = unpack_h2(q0);
    float2 z23 = unpack_h2(q1);
    float2 z45 = unpack_h2(q2);
    float2 z67 = unpack_h2(q3);
    float2 w_  = unpack_h2(q4);
    acc += w_.x;
    acc = fmaf(e01.x, z01.x, acc);
    acc = fmaf(e01.y, z01.y, acc);
    acc = fmaf(e23.x, z23.x, acc);
    acc = fmaf(e23.y, z23.y, acc);
    acc = fmaf(e45.x, z45.x, acc);
    acc = fmaf(e45.y, z45.y, acc);
    acc = fmaf(e67.x, z67.x, acc);
    acc = fmaf(e67.y, z67.y, acc);
}

// ---------------------------------------------------------------------------
// agg: 16 lanes per node; x2 unrolled dual accumulators.
// MODE 0: write pre-ReLU acc to buf (fallback path)
// MODE 1: fuse next layer's prep — 16 shfls gather the node row from the
//         wave, then prep_core writes zw_next/rb_next (no buf write).
// MODE 2: fuse the output head.
// ---------------------------------------------------------------------------
template <int MODE>
__global__ __launch_bounds__(256)
void agg_kernel(const int* __restrict__ offs,       // [N+1]
                const Rec* __restrict__ csr,        // [E] 24B records
                const unsigned* __restrict__ zw_h,  // [N,5,16] half2 (layer l)
                float* __restrict__ buf,            // rb input (layer l)
                unsigned* __restrict__ zw_next,     // MODE1: layer l+1 zw
                float* __restrict__ rb_next,        // MODE1: layer l+1 rb
                const float* __restrict__ nnW,      // MODE1: next-layer params
                const float* __restrict__ nnb,
                const float* __restrict__ rootW,
                const float* __restrict__ bias,
                const float* __restrict__ gf,       // MODE2
                const float* __restrict__ hW,       // MODE2
                const float* __restrict__ hb,       // MODE2
                float* __restrict__ out) {          // MODE2
    int tid = threadIdx.x;
    int o = tid & 15;
    int n = blockIdx.x * 16 + (tid >> 4);
    if (n >= N_NODES) return;

    float acc0 = buf[n * HID + o];
    float acc1 = 0.0f;
    int jb = offs[n], je = offs[n + 1];
    int j = jb;
    for (; j + 1 < je; j += 2) {
        Rec r0 = csr[j];
        Rec r1 = csr[j + 1];
        uint4v a0 = {r0.e0, r0.e1, r0.e2, r0.e3};
        uint4v a1 = {r1.e0, r1.e1, r1.e2, r1.e3};
        edge_accum(zw_h + (size_t)r0.src * 80, a0, o, acc0);
        edge_accum(zw_h + (size_t)r1.src * 80, a1, o, acc1);
    }
    if (j < je) {
        Rec r0 = csr[j];
        uint4v a0 = {r0.e0, r0.e1, r0.e2, r0.e3};
        edge_accum(zw_h + (size_t)r0.src * 80, a0, o, acc0);
    }
    float acc = acc0 + acc1;

    if (MODE == 0) {
        buf[n * HID + o] = acc;
    } else if (MODE == 1) {
        // gather this node's full pre-ReLU row from the 16-lane group (in-wave)
        int lane_base = (tid & 63) & ~15;
        float xv[IN_DIM];
#pragma unroll
        for (int i = 0; i < IN_DIM; ++i) {
            float v = __shfl(acc, lane_base + i, 64);
            xv[i] = fmaxf(v, 0.0f);
        }
        prep_core(xv, n, o, nnW, nnb, rootW, bias, zw_next, rb_next);
    } else {
        float h = fmaxf(acc, 0.0f) * hW[o];
        if (o < GRAPH_DIM) h = fmaf(gf[o * N_NODES + n], hW[HID + o], h);
#pragma unroll
        for (int off = 8; off > 0; off >>= 1) h += __shfl_xor(h, off, 16);
        if (o == 0) out[n] = h + hb[0];
    }
}

extern "C" void kernel_launch(void* const* d_in, const int* in_sizes, int n_in,
                              void* d_out, int out_size, void* d_ws, size_t ws_size,
                              hipStream_t stream) {
    const float* x     = (const float*)d_in[0];
    const int*   ei    = (const int*)d_in[1];
    const float* ea    = (const float*)d_in[2];
    const float* gf    = (const float*)d_in[3];
    const float* nnW   = (const float*)d_in[4];
    const float* nnb   = (const float*)d_in[5];
    const float* rootW = (const float*)d_in[6];
    const float* bias  = (const float*)d_in[7];
    const float* hW    = (const float*)d_in[8];
    const float* hb    = (const float*)d_in[9];
    float* out = (float*)d_out;

    dim3 blk(256);
    dim3 grid_e(HIST_BLOCKS);                    // 3125
    dim3 grid_hp(HIST_BLOCKS + PREP_BLOCKS);     // 6250
    dim3 grid_no(PREP_BLOCKS);                   // 3125
    dim3 grid_a((N_NODES + 15) / 16);            // 3125

    // fused path needs double-buffered zw: 16+16+19.2+3.2+3.2+~0.5 MB
    const size_t need_fused = (size_t)N_NODES * 80 * 4 * 2      // zw0+zw1
                            + (size_t)N_EDGES * sizeof(Rec)     // csr
                            + (size_t)N_NODES * HID * 4 * 2     // bufA+bufB
                            + (size_t)(N_NODES * 2 + 64) * 4;   // deg+offs+bsum

    if (ws_size >= need_fused) {
        // ---- fused 8-dispatch path ----
        unsigned* zw0 = (unsigned*)d_ws;
        unsigned* zw1 = zw0 + (size_t)N_NODES * 80;
        Rec* csr   = (Rec*)(zw1 + (size_t)N_NODES * 80);
        float* bufA = (float*)((char*)csr + (size_t)N_EDGES * sizeof(Rec));
        float* bufB = bufA + (size_t)N_NODES * HID;
        int* deg    = (int*)(bufB + (size_t)N_NODES * HID);
        int* offs   = deg + N_NODES;
        int* bsum   = offs + N_NODES + 8;

        hipMemsetAsync(deg, 0, N_NODES * sizeof(int), stream);
        hist_prep0_kernel<<<grid_hp, blk, 0, stream>>>(ei, deg, x, nnW, nnb, rootW,
                                                       bias, zw0, bufA);
        scan1_kernel<<<SCAN_NB, SCAN_BS, 0, stream>>>(deg, offs, bsum);
        scan23_kernel<<<SCAN_NB, SCAN_BS, 0, stream>>>(offs, bsum, deg);
        fill_kernel<<<grid_e, blk, 0, stream>>>(ei, ea, deg, csr);

        // agg(l=0) + prep(l=1): reads zw0/bufA, writes zw1/bufB
        agg_kernel<1><<<grid_a, blk, 0, stream>>>(offs, csr, zw0, bufA, zw1, bufB,
                                                  nnW + 2048, nnb + 256, rootW + 256,
                                                  bias + 16,
                                                  nullptr, nullptr, nullptr, nullptr);
        // agg(l=1) + prep(l=2): reads zw1/bufB, writes zw0/bufA
        agg_kernel<1><<<grid_a, blk, 0, stream>>>(offs, csr, zw1, bufB, zw0, bufA,
                                                  nnW + 4096, nnb + 512, rootW + 512,
                                                  bias + 32,
                                                  nullptr, nullptr, nullptr, nullptr);
        // agg(l=2) + head: reads zw0/bufA
        agg_kernel<2><<<grid_a, blk, 0, stream>>>(offs, csr, zw0, bufA,
                                                  nullptr, nullptr, nullptr, nullptr,
                                                  nullptr, nullptr, gf, hW, hb, out);
    } else {
        // ---- fallback: proven round-14 10-dispatch path (42 MB) ----
        unsigned* zw0 = (unsigned*)d_ws;
        Rec* csr   = (Rec*)(zw0 + (size_t)N_NODES * 80);
        float* bufA = (float*)((char*)csr + (size_t)N_EDGES * sizeof(Rec));
        float* bufB = bufA + (size_t)N_NODES * HID;
        int* deg    = (int*)(bufB + (size_t)N_NODES * HID);
        int* offs   = deg + N_NODES;
        int* bsum   = offs + N_NODES + 8;

        hipMemsetAsync(deg, 0, N_NODES * sizeof(int), stream);
        hist_prep0_kernel<<<grid_hp, blk, 0, stream>>>(ei, deg, x, nnW, nnb, rootW,
                                                       bias, zw0, bufA);
        scan1_kernel<<<SCAN_NB, SCAN_BS, 0, stream>>>(deg, offs, bsum);
        scan23_kernel<<<SCAN_NB, SCAN_BS, 0, stream>>>(offs, bsum, deg);
        fill_kernel<<<grid_e, blk, 0, stream>>>(ei, ea, deg, csr);

        agg_kernel<0><<<grid_a, blk, 0, stream>>>(offs, csr, zw0, bufA,
                                                  nullptr, nullptr, nullptr, nullptr,
                                                  nullptr, nullptr,
                                                  nullptr, nullptr, nullptr, nullptr);
        prep_kernel<<<grid_no, blk, 0, stream>>>(bufA, nnW + 2048, nnb + 256,
                                                 rootW + 256, bias + 16, zw0, bufB);
        agg_kernel<0><<<grid_a, blk, 0, stream>>>(offs, csr, zw0, bufB,
                                                  nullptr, nullptr, nullptr, nullptr,
                                                  nullptr, nullptr,
                                                  nullptr, nullptr, nullptr, nullptr);
        prep_kernel<<<grid_no, blk, 0, stream>>>(bufB, nnW + 4096, nnb + 512,
                                                 rootW + 512, bias + 32, zw0, bufA);
        agg_kernel<2><<<grid_a, blk, 0, stream>>>(offs, csr, zw0, bufA,
                                                  nullptr, nullptr, nullptr, nullptr,
                                                  nullptr, nullptr, gf, hW, hb, out);
    }
}